// Round 6
// baseline (202.953 us; speedup 1.0000x reference)
//
#include <hip/hip_runtime.h>
#include <math.h>

#define SEQ   3072
#define DM    1024
#define NH    16
#define DH    64
#define WIN   128
#define DIL   4
#define TSUB  768      // SEQ / DIL

typedef __attribute__((ext_vector_type(8))) short    short8;   // 8 bf16
typedef __attribute__((ext_vector_type(8))) _Float16 half8;    // 8 fp16
typedef __attribute__((ext_vector_type(4))) float    floatx4;  // MFMA C/D
typedef __attribute__((ext_vector_type(2))) unsigned int uint2v; // NT-store payload

__device__ __forceinline__ float bf2f(unsigned short u) {
    return __uint_as_float(((unsigned)u) << 16);
}
__device__ __forceinline__ unsigned short f2bf(float f) {   // RNE, finite inputs
    unsigned u = __float_as_uint(f);
    return (unsigned short)((u + 0x7FFFu + ((u >> 16) & 1u)) >> 16);
}
__device__ __forceinline__ unsigned short f2h(float f) {
    _Float16 h = (_Float16)f;
    return __builtin_bit_cast(unsigned short, h);
}

// async global->LDS, 16B/lane; HW places lane i at ldsbase + i*16.
__device__ __forceinline__ void gload_lds16(const void* g, void* l) {
    __builtin_amdgcn_global_load_lds(
        (const __attribute__((address_space(1))) void*)g,
        (__attribute__((address_space(3))) void*)l, 16, 0, 0);
}

// ---------------------------------------------------------------------------
// fp32 -> bf16 conversion. NT stores: converted tensors are produced once and
// consumed by blocks on other XCDs -> push to L3/HBM instead of dirty L2.
// ---------------------------------------------------------------------------
__global__ __launch_bounds__(256) void convert_kernel(
    const float* __restrict__ x,  const float* __restrict__ Wq,
    const float* __restrict__ Wk, const float* __restrict__ Wv,
    const float* __restrict__ Wo,
    ushort* __restrict__ xb,  ushort* __restrict__ Wqb,
    ushort* __restrict__ Wkb, ushort* __restrict__ Wvb,
    ushort* __restrict__ Wob)
{
    const float* s; ushort* d; int n;
    switch (blockIdx.y) {
        case 0: s = x;  d = xb;  n = SEQ * DM; break;
        case 1: s = Wq; d = Wqb; n = DM * DM;  break;
        case 2: s = Wk; d = Wkb; n = DM * DM;  break;
        case 3: s = Wv; d = Wvb; n = DM * DM;  break;
        default: s = Wo; d = Wob; n = DM * DM; break;
    }
    int i = (blockIdx.x * 256 + threadIdx.x) * 4;
    if (i >= n) return;
    float4 v = *(const float4*)&s[i];
    ushort4 o = { f2bf(v.x), f2bf(v.y), f2bf(v.z), f2bf(v.w) };
    uint2v p = __builtin_bit_cast(uint2v, o);
    __builtin_nontemporal_store(p, (uint2v*)&d[i]);
}

// ---------------------------------------------------------------------------
// bf16 MFMA GEMM, 128x64 tile, BK=32, 2-stage LDS double-buffer, ONE
// __syncthreads per K-iter (prefetch issued before compute; the barrier's
// vmcnt drain overlaps compute, and 4-5 resident blocks/CU cover the rest).
// Staging is XOR-swizzled on the global side: lane l reads chunk
// (l%4)^((l/4)&3) of its row, so the unpadded LDS tile gives <=2-way banks
// on b128 frag reads (was 4-way -> 2.36M conflict cycles in R3/R4).
// 4 waves as 2x2 over (128,64): wave tile 64x32, 4x2 MFMAs of 16x16x32.
// LDS = 2*(8KB+4KB) = 24KB -> ~5 blocks/CU with ~90 VGPR.
// ---------------------------------------------------------------------------
template<bool BF16OUT, bool QSCALE>
__device__ __forceinline__ void mfma_gemm(const ushort* __restrict__ A,
                                          const ushort* __restrict__ W,
                                          const float* __restrict__ bias,
                                          const float* __restrict__ beta,
                                          void* __restrict__ Cv,
                                          int bx, int by)
{
    __shared__ ushort As[2][128][32];   // 16 KB
    __shared__ ushort Bs[2][64][32];    //  8 KB

    const int tid  = threadIdx.x;
    const int lane = tid & 63, w = tid >> 6;
    const int ln15 = lane & 15, quad = lane >> 4;
    const int wm = w >> 1, wn = w & 1;

    // glds staging: lane -> (row = l/4, chunk = (l%4) ^ ((l/4)&3), 8 bf16/chunk)
    const int srow = lane >> 2;
    const int schk = (lane & 3) ^ (srow & 3);
    const ushort* aP0 = A + (size_t)(by * 128 + 32 * w + srow) * DM + schk * 8;
    const ushort* aP1 = aP0 + 16 * DM;
    const ushort* bP  = W + (size_t)(bx * 64 + 16 * w + srow) * DM + schk * 8;

    const floatx4 zero = {0.f, 0.f, 0.f, 0.f};
    floatx4 acc[4][2];
#pragma unroll
    for (int i = 0; i < 4; ++i)
#pragma unroll
        for (int j = 0; j < 2; ++j) acc[i][j] = zero;

    // prologue: tile 0 -> stage 0
    gload_lds16(aP0, &As[0][32 * w][0]);
    gload_lds16(aP1, &As[0][32 * w + 16][0]);
    gload_lds16(bP,  &Bs[0][16 * w][0]);
    __syncthreads();

    const int rsw = (ln15 & 3);           // frag-read swizzle key
#pragma unroll 4
    for (int k = 0; k < 32; ++k) {
        const int st = k & 1, sn = st ^ 1;
        if (k < 31) {                     // prefetch tile k+1 into other stage
            gload_lds16(aP0 + (k + 1) * 32, &As[sn][32 * w][0]);
            gload_lds16(aP1 + (k + 1) * 32, &As[sn][32 * w + 16][0]);
            gload_lds16(bP  + (k + 1) * 32, &Bs[sn][16 * w][0]);
        }
        short8 af[4], bf[2];
#pragma unroll
        for (int i = 0; i < 4; ++i)
            af[i] = *(const short8*)&As[st][wm * 64 + i * 16 + ln15][(quad ^ rsw) * 8];
#pragma unroll
        for (int j = 0; j < 2; ++j)
            bf[j] = *(const short8*)&Bs[st][wn * 32 + j * 16 + ln15][(quad ^ rsw) * 8];
#pragma unroll
        for (int i = 0; i < 4; ++i)
#pragma unroll
            for (int j = 0; j < 2; ++j)
                acc[i][j] = __builtin_amdgcn_mfma_f32_16x16x32_bf16(af[i], bf[j], acc[i][j], 0, 0, 0);
        __syncthreads();                  // tile k+1 resident; stage st reusable
    }

#pragma unroll
    for (int j = 0; j < 2; ++j) {
        const int col = bx * 64 + wn * 32 + j * 16 + ln15;
        const float b = bias[col];
        const float scale = QSCALE ? 0.125f * __expf(-beta[col >> 6]) : 1.0f;
#pragma unroll
        for (int i = 0; i < 4; ++i) {
            const int row0 = by * 128 + wm * 64 + i * 16 + quad * 4;
#pragma unroll
            for (int rg = 0; rg < 4; ++rg) {
                float vv = (acc[i][j][rg] + b) * scale;
                if (BF16OUT)
                    __builtin_nontemporal_store(f2bf(vv),
                        (ushort*)Cv + (size_t)(row0 + rg) * DM + col);
                else
                    __builtin_nontemporal_store(vv,
                        (float*)Cv + (size_t)(row0 + rg) * DM + col);
            }
        }
    }
}

// grid (16, 24, 3): z selects Q/K/V. 1152 blocks (~4.5/CU).
__global__ __launch_bounds__(256) void qkv_kernel(
    const ushort* __restrict__ xb,
    const ushort* __restrict__ Wqb, const float* __restrict__ bq,
    const ushort* __restrict__ Wkb, const float* __restrict__ bk,
    const ushort* __restrict__ Wvb, const float* __restrict__ bv,
    const float* __restrict__ beta,
    ushort* __restrict__ q, ushort* __restrict__ k, ushort* __restrict__ v)
{
    const int z = blockIdx.z;
    const ushort* W = (z == 0) ? Wqb : (z == 1) ? Wkb : Wvb;
    const float*  b = (z == 0) ? bq  : (z == 1) ? bk  : bv;
    ushort*       C = (z == 0) ? q   : (z == 1) ? k   : v;
    if (z == 0)
        mfma_gemm<true, true >(xb, W, b, beta, C, blockIdx.x, blockIdx.y);
    else
        mfma_gemm<true, false>(xb, W, b, nullptr, C, blockIdx.x, blockIdx.y);
}

// grid (16, 24): 384 blocks.
__global__ __launch_bounds__(256) void out_kernel(
    const ushort* __restrict__ ctxb, const ushort* __restrict__ Wob,
    const float* __restrict__ bo, float* __restrict__ out)
{
    mfma_gemm<false, false>(ctxb, Wob, bo, nullptr, out, blockIdx.x, blockIdx.y);
}

// ---------------------------------------------------------------------------
// MFMA attention (unchanged from R3; ctx stores NT for the cross-XCD handoff).
// ---------------------------------------------------------------------------
struct AttnSmem {
    union {
        ushort Ks[192 * 64];        // [key][dg] ; dg holds dims 8*(dg^(key&7))
        ushort Vt[6 * 4 * 64 * 8];  // [kc][dt][lane][8] fp16, lane-linear
    } u;
    float S[32][195];
    float Rsum[32];
};

__global__ __launch_bounds__(256) void attn_kernel(
    const ushort* __restrict__ q, const ushort* __restrict__ k,
    const ushort* __restrict__ v, ushort* __restrict__ ctx)
{
    __shared__ AttnSmem sm;

    const int tid  = threadIdx.x;
    const int lane = tid & 63, w = tid >> 6;
    const int ln15 = lane & 15, quad = lane >> 4;
    const int t0   = blockIdx.x * 32;
    const int r    = blockIdx.y;
    const int h    = blockIdx.z;
    const int hoff = h * DH;

    // ---- stage K (192 keys x 64 dims) via glds, 6 ops/wave -----------------
    {
        const int kr = lane >> 3;                   // key-in-op 0..7
        const int swz = ((lane & 7) ^ kr) * 8;      // XOR swizzle on global dim
#pragma unroll
        for (int ci = w * 6; ci < w * 6 + 6; ++ci) {
            int key = ci * 8 + kr;
            long grow = 4L * (t0 - 160 + key) + r;  // may be negative -> q buffer
            gload_lds16(k + grow * DM + hoff + swz, &sm.u.Ks[ci * 512]);
        }
    }

    // ---- Q A-frags direct from global (wave w owns qtile w>>1) -------------
    const int qt = w >> 1;
    short8 qf0, qf1;
    {
        int qrow = qt * 16 + ln15;
        const ushort* gq = q + (4L * (t0 + qrow) + r) * DM + hoff + quad * 8;
        qf0 = *(const short8*)gq;
        qf1 = *(const short8*)(gq + 32);
    }

    // ---- V loads into registers (writes to LDS deferred past barrier 2) ----
    short8 vreg[6];
#pragma unroll
    for (int it = 0; it < 6; ++it) {
        int idx = it * 256 + tid;                   // 0..1535
        int key = idx >> 3, d0 = (idx & 7) * 8;
        long grow = 4L * (t0 - 160 + key) + r;
        vreg[it] = *(const short8*)(v + grow * DM + hoff + d0);
    }

    __syncthreads();   // barrier 1: Ks staged (vmcnt drained by sync)

    // ---- QK^T: wave w -> qtile w>>1, ktiles (w&1)*6 .. +5 ------------------
    {
        const floatx4 zero = {0.f, 0.f, 0.f, 0.f};
        const int kt0 = (w & 1) * 6;
        const int lb  = ln15 & 7;
#pragma unroll
        for (int kk2 = 0; kk2 < 6; ++kk2) {
            const int kt  = kt0 + kk2;
            const int key = kt * 16 + ln15;
            short8 b0 = *(const short8*)&sm.u.Ks[key * 64 + ((quad ^ lb) << 3)];
            short8 b1 = *(const short8*)&sm.u.Ks[key * 64 + (((4 + quad) ^ lb) << 3)];
            floatx4 acc = zero;
            acc = __builtin_amdgcn_mfma_f32_16x16x32_bf16(qf0, b0, acc, 0, 0, 0);
            acc = __builtin_amdgcn_mfma_f32_16x16x32_bf16(qf1, b1, acc, 0, 0, 0);
            const int tp = t0 - 160 + key;          // key slot time
#pragma unroll
            for (int rg = 0; rg < 4; ++rg) {
                int qrow = qt * 16 + quad * 4 + rg;
                int tq = t0 + qrow;
                bool ok = (tp >= 0) && (tp <= tq) && (tp > tq - WIN);
                sm.S[qrow][key] = ok ? acc[rg] : -1e30f;
            }
        }
    }

    __syncthreads();   // barrier 2: S complete, Ks reads done (Vt may alias)

    // ---- V transpose -> frag-linear fp16 LDS -------------------------------
#pragma unroll
    for (int it = 0; it < 6; ++it) {
        int idx = it * 256 + tid;
        int key = idx >> 3, d0 = (idx & 7) * 8;
        int kc = key >> 5, qd = (key >> 3) & 3, jj = key & 7;
        short8 sv = vreg[it];
#pragma unroll
        for (int u = 0; u < 8; ++u) {
            int dim = d0 + u, dt = dim >> 4, ln = dim & 15;
            sm.u.Vt[(kc * 4 + dt) * 512 + (qd * 16 + ln) * 8 + jj] =
                f2h(bf2f((unsigned short)sv[u]));
        }
    }

    // ---- softmax: 8 threads/row, stride-8 slot ownership -------------------
    {
        const int sq = tid >> 3, part = tid & 7;
        float m = -1e30f;
#pragma unroll
        for (int j = 0; j < 24; ++j) m = fmaxf(m, sm.S[sq][part + 8 * j]);
#pragma unroll
        for (int o = 1; o < 8; o <<= 1) m = fmaxf(m, __shfl_xor(m, o));
        float sum = 0.f;
#pragma unroll
        for (int j = 0; j < 24; ++j) {
            int ks = part + 8 * j;
            float e = __expf(sm.S[sq][ks] - m);
            sm.S[sq][ks] = e;
            sum += e;
        }
#pragma unroll
        for (int o = 1; o < 8; o <<= 1) sum += __shfl_xor(sum, o);
        if (part == 0) sm.Rsum[sq] = 1.0f / sum;
    }

    __syncthreads();   // barrier 3: Vt + P(S) + Rsum ready

    // ---- PV: wave w -> qtile w&1, dtiles (w>>1)*2 .. +1 --------------------
    {
        const floatx4 zero = {0.f, 0.f, 0.f, 0.f};
        const int qtp = w & 1, dh = w >> 1;
        floatx4 o0 = zero, o1 = zero;
#pragma unroll
        for (int kc = 0; kc < 6; ++kc) {
            const float* ps = &sm.S[qtp * 16 + ln15][kc * 32 + quad * 8];
            half8 pa;
#pragma unroll
            for (int u = 0; u < 8; ++u) pa[u] = (_Float16)ps[u];
            half8 vb0 = *(const half8*)&sm.u.Vt[(kc * 4 + dh * 2 + 0) * 512 + lane * 8];
            half8 vb1 = *(const half8*)&sm.u.Vt[(kc * 4 + dh * 2 + 1) * 512 + lane * 8];
            o0 = __builtin_amdgcn_mfma_f32_16x16x32_f16(pa, vb0, o0, 0, 0, 0);
            o1 = __builtin_amdgcn_mfma_f32_16x16x32_f16(pa, vb1, o1, 0, 0, 0);
        }
#pragma unroll
        for (int rg = 0; rg < 4; ++rg) {
            int qrow = qtp * 16 + quad * 4 + rg;
            float rs = sm.Rsum[qrow];
            long orow = 4L * (t0 + qrow) + r;
            ushort* cp = ctx + orow * DM + hoff + dh * 32 + ln15;
            __builtin_nontemporal_store(f2bf(o0[rg] * rs), cp);
            __builtin_nontemporal_store(f2bf(o1[rg] * rs), cp + 16);
        }
    }
}

// ---------------------------------------------------------------------------
// ws layout (all bf16): q, k, v, ctx (SEQ*DM each), x, Wq, Wk, Wv, Wo.
// ---------------------------------------------------------------------------
extern "C" void kernel_launch(void* const* d_in, const int* in_sizes, int n_in,
                              void* d_out, int out_size, void* d_ws, size_t ws_size,
                              hipStream_t stream)
{
    const float* x    = (const float*)d_in[0];
    const float* beta = (const float*)d_in[1];
    const float* Wq   = (const float*)d_in[2];
    const float* bq   = (const float*)d_in[3];
    const float* Wk   = (const float*)d_in[4];
    const float* bk   = (const float*)d_in[5];
    const float* Wv   = (const float*)d_in[6];
    const float* bv   = (const float*)d_in[7];
    const float* Wo   = (const float*)d_in[8];
    const float* bo   = (const float*)d_in[9];

    ushort* qb   = (ushort*)d_ws;
    ushort* kb   = qb   + (size_t)SEQ * DM;
    ushort* vb   = kb   + (size_t)SEQ * DM;
    ushort* ctxb = vb   + (size_t)SEQ * DM;
    ushort* xb   = ctxb + (size_t)SEQ * DM;
    ushort* Wqb  = xb   + (size_t)SEQ * DM;
    ushort* Wkb  = Wqb  + (size_t)DM * DM;
    ushort* Wvb  = Wkb  + (size_t)DM * DM;
    ushort* Wob  = Wvb  + (size_t)DM * DM;
    float*  out  = (float*)d_out;

    dim3 gcv(SEQ * DM / 4 / 256, 5);
    convert_kernel<<<gcv, 256, 0, stream>>>(x, Wq, Wk, Wv, Wo, xb, Wqb, Wkb, Wvb, Wob);

    dim3 gqkv(DM / 64, SEQ / 128, 3);           // (16, 24, 3) = 1152 blocks
    qkv_kernel<<<gqkv, 256, 0, stream>>>(xb, Wqb, bq, Wkb, bk, Wvb, bv, beta, qb, kb, vb);

    dim3 gattn(TSUB / 32, DIL, NH);             // (24, 4, 16)
    attn_kernel<<<gattn, 256, 0, stream>>>(qb, kb, vb, ctxb);

    dim3 gout(DM / 64, SEQ / 128);              // (16, 24) = 384 blocks
    out_kernel<<<gout, 256, 0, stream>>>(ctxb, Wob, bo, out);
}

// Round 7
// 184.947 us; speedup vs baseline: 1.0974x; 1.0974x over previous
//
#include <hip/hip_runtime.h>
#include <math.h>

#define SEQ   3072
#define DM    1024
#define NH    16
#define DH    64
#define WIN   128
#define DIL   4
#define TSUB  768      // SEQ / DIL

typedef __attribute__((ext_vector_type(8))) short    short8;   // 8 bf16
typedef __attribute__((ext_vector_type(8))) _Float16 half8;    // 8 fp16
typedef __attribute__((ext_vector_type(4))) float    floatx4;  // MFMA C/D

__device__ __forceinline__ float bf2f(unsigned short u) {
    return __uint_as_float(((unsigned)u) << 16);
}
__device__ __forceinline__ unsigned short f2bf(float f) {   // RNE, finite inputs
    unsigned u = __float_as_uint(f);
    return (unsigned short)((u + 0x7FFFu + ((u >> 16) & 1u)) >> 16);
}
__device__ __forceinline__ unsigned short f2h(float f) {
    _Float16 h = (_Float16)f;
    return __builtin_bit_cast(unsigned short, h);
}

// async global->LDS, 16B/lane (used only by attn's K staging).
__device__ __forceinline__ void gload_lds16(const void* g, void* l) {
    __builtin_amdgcn_global_load_lds(
        (const __attribute__((address_space(1))) void*)g,
        (__attribute__((address_space(3))) void*)l, 16, 0, 0);
}

// ---------------------------------------------------------------------------
// fp32 -> bf16 conversion. Plain stores (R6 post-mortem: NT pushed data to
// HBM and the consumers paid it back with interest).
// ---------------------------------------------------------------------------
__global__ __launch_bounds__(256) void convert_kernel(
    const float* __restrict__ x,  const float* __restrict__ Wq,
    const float* __restrict__ Wk, const float* __restrict__ Wv,
    const float* __restrict__ Wo,
    ushort* __restrict__ xb,  ushort* __restrict__ Wqb,
    ushort* __restrict__ Wkb, ushort* __restrict__ Wvb,
    ushort* __restrict__ Wob)
{
    const float* s; ushort* d; int n;
    switch (blockIdx.y) {
        case 0: s = x;  d = xb;  n = SEQ * DM; break;
        case 1: s = Wq; d = Wqb; n = DM * DM;  break;
        case 2: s = Wk; d = Wkb; n = DM * DM;  break;
        case 3: s = Wv; d = Wvb; n = DM * DM;  break;
        default: s = Wo; d = Wob; n = DM * DM; break;
    }
    int i = (blockIdx.x * 256 + threadIdx.x) * 4;
    if (i >= n) return;
    float4 v = *(const float4*)&s[i];
    ushort4 o = { f2bf(v.x), f2bf(v.y), f2bf(v.z), f2bf(v.w) };
    *(ushort4*)&d[i] = o;
}

// ---------------------------------------------------------------------------
// bf16 MFMA GEMM, 128x128 tile, BK=32, reg-staged pipeline:
//   loop k: [global_load k+1 -> regs] [compute k from LDS] [barrier]
//           [ds_write k+1] [barrier]
// The vmcnt wait for the k+1 loads sits AFTER compute k (at the ds_write) --
// load latency is covered by the 32 MFMAs, unlike the glds structures
// (R3/R4/R6) whose drain preceded compute. Single 16 KB LDS buffer.
// LDS layout: chunk c (8 bf16) of row r stored at position c ^ ((r>>1)&3);
// both ds_write_b128 and frag ds_read_b128 hit the 2-way floor (free).
// 4 waves as 2x2, wave tile 64x64, 4x4 MFMAs of 16x16x32.
// ---------------------------------------------------------------------------
template<bool BF16OUT, bool QSCALE>
__device__ __forceinline__ void mfma_gemm(const ushort* __restrict__ A,
                                          const ushort* __restrict__ W,
                                          const float* __restrict__ bias,
                                          const float* __restrict__ beta,
                                          void* __restrict__ Cv,
                                          int bx, int by)
{
    __shared__ ushort As[128][32];   // 8 KB, swizzled chunks
    __shared__ ushort Bs[128][32];   // 8 KB

    const int tid  = threadIdx.x;
    const int lane = tid & 63, w = tid >> 6;
    const int ln15 = lane & 15, quad = lane >> 4;
    const int wm = w >> 1, wn = w & 1;

    // staging: thread t -> row t>>1, chunks {2h, 2h+1} where h = t&1
    const int srow = tid >> 1;
    const int sh   = tid & 1;
    const int sf   = (srow >> 1) & 3;                 // swizzle key
    const ushort* aG = A + (size_t)(by * 128 + srow) * DM + sh * 16;
    const ushort* bG = W + (size_t)(bx * 128 + srow) * DM + sh * 16;
    ushort* aL0 = &As[srow][((2 * sh)     ^ sf) * 8];
    ushort* aL1 = &As[srow][((2 * sh + 1) ^ sf) * 8];
    ushort* bL0 = &Bs[srow][((2 * sh)     ^ sf) * 8];
    ushort* bL1 = &Bs[srow][((2 * sh + 1) ^ sf) * 8];

    const floatx4 zero = {0.f, 0.f, 0.f, 0.f};
    floatx4 acc[4][4];
#pragma unroll
    for (int i = 0; i < 4; ++i)
#pragma unroll
        for (int j = 0; j < 4; ++j) acc[i][j] = zero;

    // prologue: tile 0 regs -> LDS
    short8 ra0 = *(const short8*)aG,       ra1 = *(const short8*)(aG + 8);
    short8 rb0 = *(const short8*)bG,       rb1 = *(const short8*)(bG + 8);
    *(short8*)aL0 = ra0; *(short8*)aL1 = ra1;
    *(short8*)bL0 = rb0; *(short8*)bL1 = rb1;
    __syncthreads();

    const int rf = (ln15 >> 1) & 3;       // frag-read swizzle key (lane-const)
#pragma unroll 2
    for (int k = 0; k < 32; ++k) {
        if (k < 31) {                     // loads for tile k+1 (regs)
            const ushort* aN = aG + (k + 1) * 32;
            const ushort* bN = bG + (k + 1) * 32;
            ra0 = *(const short8*)aN; ra1 = *(const short8*)(aN + 8);
            rb0 = *(const short8*)bN; rb1 = *(const short8*)(bN + 8);
        }
        short8 af[4], bf[4];
#pragma unroll
        for (int i = 0; i < 4; ++i)
            af[i] = *(const short8*)&As[wm * 64 + i * 16 + ln15][(quad ^ rf) * 8];
#pragma unroll
        for (int j = 0; j < 4; ++j)
            bf[j] = *(const short8*)&Bs[wn * 64 + j * 16 + ln15][(quad ^ rf) * 8];
#pragma unroll
        for (int i = 0; i < 4; ++i)
#pragma unroll
            for (int j = 0; j < 4; ++j)
                acc[i][j] = __builtin_amdgcn_mfma_f32_16x16x32_bf16(af[i], bf[j], acc[i][j], 0, 0, 0);

        __syncthreads();                  // tile-k LDS reads complete
        if (k < 31) {                     // vmcnt wait lands HERE (post-compute)
            *(short8*)aL0 = ra0; *(short8*)aL1 = ra1;
            *(short8*)bL0 = rb0; *(short8*)bL1 = rb1;
        }
        __syncthreads();                  // tile k+1 resident
    }

#pragma unroll
    for (int j = 0; j < 4; ++j) {
        const int col = bx * 128 + wn * 64 + j * 16 + ln15;
        const float b = bias[col];
        const float scale = QSCALE ? 0.125f * __expf(-beta[col >> 6]) : 1.0f;
#pragma unroll
        for (int i = 0; i < 4; ++i) {
            const int row0 = by * 128 + wm * 64 + i * 16 + quad * 4;
#pragma unroll
            for (int rg = 0; rg < 4; ++rg) {
                float vv = (acc[i][j][rg] + b) * scale;
                if (BF16OUT)
                    ((ushort*)Cv)[(size_t)(row0 + rg) * DM + col] = f2bf(vv);
                else
                    ((float*)Cv)[(size_t)(row0 + rg) * DM + col] = vv;
            }
        }
    }
}

// grid (8, 24, 3): z selects Q/K/V. 576 blocks.
__global__ __launch_bounds__(256) void qkv_kernel(
    const ushort* __restrict__ xb,
    const ushort* __restrict__ Wqb, const float* __restrict__ bq,
    const ushort* __restrict__ Wkb, const float* __restrict__ bk,
    const ushort* __restrict__ Wvb, const float* __restrict__ bv,
    const float* __restrict__ beta,
    ushort* __restrict__ q, ushort* __restrict__ k, ushort* __restrict__ v)
{
    const int z = blockIdx.z;
    const ushort* W = (z == 0) ? Wqb : (z == 1) ? Wkb : Wvb;
    const float*  b = (z == 0) ? bq  : (z == 1) ? bk  : bv;
    ushort*       C = (z == 0) ? q   : (z == 1) ? k   : v;
    if (z == 0)
        mfma_gemm<true, true >(xb, W, b, beta, C, blockIdx.x, blockIdx.y);
    else
        mfma_gemm<true, false>(xb, W, b, nullptr, C, blockIdx.x, blockIdx.y);
}

// grid (8, 24): 192 blocks.
__global__ __launch_bounds__(256) void out_kernel(
    const ushort* __restrict__ ctxb, const ushort* __restrict__ Wob,
    const float* __restrict__ bo, float* __restrict__ out)
{
    mfma_gemm<false, false>(ctxb, Wob, bo, nullptr, out, blockIdx.x, blockIdx.y);
}

// ---------------------------------------------------------------------------
// MFMA attention (structure unchanged from R3; ctx stores back to plain).
// ---------------------------------------------------------------------------
struct AttnSmem {
    union {
        ushort Ks[192 * 64];        // [key][dg] ; dg holds dims 8*(dg^(key&7))
        ushort Vt[6 * 4 * 64 * 8];  // [kc][dt][lane][8] fp16, lane-linear
    } u;
    float S[32][195];
    float Rsum[32];
};

__global__ __launch_bounds__(256) void attn_kernel(
    const ushort* __restrict__ q, const ushort* __restrict__ k,
    const ushort* __restrict__ v, ushort* __restrict__ ctx)
{
    __shared__ AttnSmem sm;

    const int tid  = threadIdx.x;
    const int lane = tid & 63, w = tid >> 6;
    const int ln15 = lane & 15, quad = lane >> 4;
    const int t0   = blockIdx.x * 32;
    const int r    = blockIdx.y;
    const int h    = blockIdx.z;
    const int hoff = h * DH;

    // ---- stage K (192 keys x 64 dims) via glds, 6 ops/wave -----------------
    {
        const int kr = lane >> 3;                   // key-in-op 0..7
        const int swz = ((lane & 7) ^ kr) * 8;      // XOR swizzle on global dim
#pragma unroll
        for (int ci = w * 6; ci < w * 6 + 6; ++ci) {
            int key = ci * 8 + kr;
            long grow = 4L * (t0 - 160 + key) + r;  // may be negative -> q buffer
            gload_lds16(k + grow * DM + hoff + swz, &sm.u.Ks[ci * 512]);
        }
    }

    // ---- Q A-frags direct from global (wave w owns qtile w>>1) -------------
    const int qt = w >> 1;
    short8 qf0, qf1;
    {
        int qrow = qt * 16 + ln15;
        const ushort* gq = q + (4L * (t0 + qrow) + r) * DM + hoff + quad * 8;
        qf0 = *(const short8*)gq;
        qf1 = *(const short8*)(gq + 32);
    }

    // ---- V loads into registers (writes to LDS deferred past barrier 2) ----
    short8 vreg[6];
#pragma unroll
    for (int it = 0; it < 6; ++it) {
        int idx = it * 256 + tid;                   // 0..1535
        int key = idx >> 3, d0 = (idx & 7) * 8;
        long grow = 4L * (t0 - 160 + key) + r;
        vreg[it] = *(const short8*)(v + grow * DM + hoff + d0);
    }

    __syncthreads();   // barrier 1: Ks staged (vmcnt drained by sync)

    // ---- QK^T: wave w -> qtile w>>1, ktiles (w&1)*6 .. +5 ------------------
    {
        const floatx4 zero = {0.f, 0.f, 0.f, 0.f};
        const int kt0 = (w & 1) * 6;
        const int lb  = ln15 & 7;
#pragma unroll
        for (int kk2 = 0; kk2 < 6; ++kk2) {
            const int kt  = kt0 + kk2;
            const int key = kt * 16 + ln15;
            short8 b0 = *(const short8*)&sm.u.Ks[key * 64 + ((quad ^ lb) << 3)];
            short8 b1 = *(const short8*)&sm.u.Ks[key * 64 + (((4 + quad) ^ lb) << 3)];
            floatx4 acc = zero;
            acc = __builtin_amdgcn_mfma_f32_16x16x32_bf16(qf0, b0, acc, 0, 0, 0);
            acc = __builtin_amdgcn_mfma_f32_16x16x32_bf16(qf1, b1, acc, 0, 0, 0);
            const int tp = t0 - 160 + key;          // key slot time
#pragma unroll
            for (int rg = 0; rg < 4; ++rg) {
                int qrow = qt * 16 + quad * 4 + rg;
                int tq = t0 + qrow;
                bool ok = (tp >= 0) && (tp <= tq) && (tp > tq - WIN);
                sm.S[qrow][key] = ok ? acc[rg] : -1e30f;
            }
        }
    }

    __syncthreads();   // barrier 2: S complete, Ks reads done (Vt may alias)

    // ---- V transpose -> frag-linear fp16 LDS -------------------------------
#pragma unroll
    for (int it = 0; it < 6; ++it) {
        int idx = it * 256 + tid;
        int key = idx >> 3, d0 = (idx & 7) * 8;
        int kc = key >> 5, qd = (key >> 3) & 3, jj = key & 7;
        short8 sv = vreg[it];
#pragma unroll
        for (int u = 0; u < 8; ++u) {
            int dim = d0 + u, dt = dim >> 4, ln = dim & 15;
            sm.u.Vt[(kc * 4 + dt) * 512 + (qd * 16 + ln) * 8 + jj] =
                f2h(bf2f((unsigned short)sv[u]));
        }
    }

    // ---- softmax: 8 threads/row, stride-8 slot ownership -------------------
    {
        const int sq = tid >> 3, part = tid & 7;
        float m = -1e30f;
#pragma unroll
        for (int j = 0; j < 24; ++j) m = fmaxf(m, sm.S[sq][part + 8 * j]);
#pragma unroll
        for (int o = 1; o < 8; o <<= 1) m = fmaxf(m, __shfl_xor(m, o));
        float sum = 0.f;
#pragma unroll
        for (int j = 0; j < 24; ++j) {
            int ks = part + 8 * j;
            float e = __expf(sm.S[sq][ks] - m);
            sm.S[sq][ks] = e;
            sum += e;
        }
#pragma unroll
        for (int o = 1; o < 8; o <<= 1) sum += __shfl_xor(sum, o);
        if (part == 0) sm.Rsum[sq] = 1.0f / sum;
    }

    __syncthreads();   // barrier 3: Vt + P(S) + Rsum ready

    // ---- PV: wave w -> qtile w&1, dtiles (w>>1)*2 .. +1 --------------------
    {
        const floatx4 zero = {0.f, 0.f, 0.f, 0.f};
        const int qtp = w & 1, dh = w >> 1;
        floatx4 o0 = zero, o1 = zero;
#pragma unroll
        for (int kc = 0; kc < 6; ++kc) {
            const float* ps = &sm.S[qtp * 16 + ln15][kc * 32 + quad * 8];
            half8 pa;
#pragma unroll
            for (int u = 0; u < 8; ++u) pa[u] = (_Float16)ps[u];
            half8 vb0 = *(const half8*)&sm.u.Vt[(kc * 4 + dh * 2 + 0) * 512 + lane * 8];
            half8 vb1 = *(const half8*)&sm.u.Vt[(kc * 4 + dh * 2 + 1) * 512 + lane * 8];
            o0 = __builtin_amdgcn_mfma_f32_16x16x32_f16(pa, vb0, o0, 0, 0, 0);
            o1 = __builtin_amdgcn_mfma_f32_16x16x32_f16(pa, vb1, o1, 0, 0, 0);
        }
#pragma unroll
        for (int rg = 0; rg < 4; ++rg) {
            int qrow = qtp * 16 + quad * 4 + rg;
            float rs = sm.Rsum[qrow];
            long orow = 4L * (t0 + qrow) + r;
            ushort* cp = ctx + orow * DM + hoff + dh * 32 + ln15;
            cp[0]  = f2bf(o0[rg] * rs);
            cp[16] = f2bf(o1[rg] * rs);
        }
    }
}

// ---------------------------------------------------------------------------
// ws layout (all bf16): q, k, v, ctx (SEQ*DM each), x, Wq, Wk, Wv, Wo.
// ---------------------------------------------------------------------------
extern "C" void kernel_launch(void* const* d_in, const int* in_sizes, int n_in,
                              void* d_out, int out_size, void* d_ws, size_t ws_size,
                              hipStream_t stream)
{
    const float* x    = (const float*)d_in[0];
    const float* beta = (const float*)d_in[1];
    const float* Wq   = (const float*)d_in[2];
    const float* bq   = (const float*)d_in[3];
    const float* Wk   = (const float*)d_in[4];
    const float* bk   = (const float*)d_in[5];
    const float* Wv   = (const float*)d_in[6];
    const float* bv   = (const float*)d_in[7];
    const float* Wo   = (const float*)d_in[8];
    const float* bo   = (const float*)d_in[9];

    ushort* qb   = (ushort*)d_ws;
    ushort* kb   = qb   + (size_t)SEQ * DM;
    ushort* vb   = kb   + (size_t)SEQ * DM;
    ushort* ctxb = vb   + (size_t)SEQ * DM;
    ushort* xb   = ctxb + (size_t)SEQ * DM;
    ushort* Wqb  = xb   + (size_t)SEQ * DM;
    ushort* Wkb  = Wqb  + (size_t)DM * DM;
    ushort* Wvb  = Wkb  + (size_t)DM * DM;
    ushort* Wob  = Wvb  + (size_t)DM * DM;
    float*  out  = (float*)d_out;

    dim3 gcv(SEQ * DM / 4 / 256, 5);
    convert_kernel<<<gcv, 256, 0, stream>>>(x, Wq, Wk, Wv, Wo, xb, Wqb, Wkb, Wvb, Wob);

    dim3 gqkv(DM / 128, SEQ / 128, 3);          // (8, 24, 3) = 576 blocks
    qkv_kernel<<<gqkv, 256, 0, stream>>>(xb, Wqb, bq, Wkb, bk, Wvb, bv, beta, qb, kb, vb);

    dim3 gattn(TSUB / 32, DIL, NH);             // (24, 4, 16)
    attn_kernel<<<gattn, 256, 0, stream>>>(qb, kb, vb, ctxb);

    dim3 gout(DM / 128, SEQ / 128);             // (8, 24) = 192 blocks
    out_kernel<<<gout, 256, 0, stream>>>(ctxb, Wob, bo, out);
}